// Round 15
// baseline (47.266 us; speedup 1.0000x reference)
//
#include <hip/hip_runtime.h>

#define N_PED  8192
#define HID    128
#define NN     36
#define IPB    8             // i-rows per block
#define SLICES 64            // j-slices per block (one per 8-thread group)
#define BLOCK  512           // IPB * SLICES
#define JS     128           // j's per thread (8192/64); counts/bin <= 127+sat
#define NB     1024          // 8192 / IPB

typedef unsigned long long u64;
typedef unsigned u32;

// Carry-save full adder over 64-bit bit-planes (pure bitwise; u64 lowers
// 1:1 to 2x 32-bit VALU ops — no selects, no branches).
#define CSA(s, r, a, b, c) do { u64 _a=(a), _b=(b), _c=(c); u64 _t=_a^_b; \
    (r) = (_a & _b) | (_t & _c); (s) = _t ^ _c; } while (0)

// One pair -> one-hot u64, asm-pinned: EXACTLY 11 VALU.
//   u1=trunc(px-xi4)-1, u2=trunc(py-yi4)-1 (NaN/inf/neg -> huge unsigned)
//   bin = valid ? u1*6+u2 : 63 (trash bit; planes are bitwise-independent)
__device__ __forceinline__ u64 onehot_asm(float px, float py,
                                          float xi4, float yi4) {
    u64 oh; u32 t0, t1, t2;
    asm("v_sub_f32 %[t0], %[px], %[xi4]\n\t"
        "v_sub_f32 %[t1], %[py], %[yi4]\n\t"
        "v_cvt_i32_f32 %[t0], %[t0]\n\t"
        "v_cvt_i32_f32 %[t1], %[t1]\n\t"
        "v_add_u32 %[t0], -1, %[t0]\n\t"
        "v_add_u32 %[t1], -1, %[t1]\n\t"
        "v_max_u32 %[t2], %[t0], %[t1]\n\t"
        "v_mad_u32_u24 %[t0], %[t0], 6, %[t1]\n\t"
        "v_cmp_gt_u32 vcc, 6, %[t2]\n\t"
        "v_cndmask_b32 %[t0], 63, %[t0], vcc\n\t"
        "v_lshlrev_b64 %[oh], %[t0], 1"
        : [oh]"=v"(oh), [t0]"=&v"(t0), [t1]"=&v"(t1), [t2]"=&v"(t2)
        : [px]"v"(px), [py]"v"(py), [xi4]"v"(xi4), [yi4]"v"(yi4)
        : "vcc");
    return oh;
}

// Add 8 one-hot items into 7 bit-planes (weights 1..64): 7 CSA + 3 half-adds
// + saturating top = 42 u64 ops = 84 VALU instr per 8 pairs.
__device__ __forceinline__ void add8(
    u64 x0, u64 x1, u64 x2, u64 x3, u64 x4, u64 x5, u64 x6, u64 x7,
    u64& R1, u64& R2, u64& R4, u64& R8, u64& R16, u64& R32, u64& R64)
{
    u64 s0,c0,s1,c1,s2,c2,c3,s4,c4,c5,c6,c7,c8,c9;
    CSA(s0, c0, x0, x1, x2);
    CSA(s1, c1, x3, x4, x5);
    CSA(s2, c2, x6, x7, s0);
    CSA(R1, c3, s1, s2, R1);          // weight-1 residue
    CSA(s4, c4, c0, c1, c2);          // weight-2 items
    CSA(R2, c5, s4, c3, R2);
    CSA(R4, c6, c4, c5, R4);          // weight-4
    c7 = R8  & c6;  R8  ^= c6;        // weight-8  half-add
    c8 = R16 & c7;  R16 ^= c7;        // weight-16
    c9 = R32 & c8;  R32 ^= c8;        // weight-32
    R64 |= c9;                        // weight-64 (saturating top)
}

// launch_bounds(512,4): ~128 VGPR budget -> no spill (R12's (512,6) forced
// VGPR=40 and spilled: FETCH 3.6MB. Single-variable fix.)
__global__ __launch_bounds__(BLOCK, 4) void pool_kernel(
    const float* __restrict__ obs2_g,   // [8192][2]
    const float* __restrict__ Wg,       // [128][36] row-major
    const float* __restrict__ bias,     // [128]
    float* __restrict__ out)            // [8192][128]
{
    __shared__ u32   s_h[9 * BLOCK];               // 18,432 B byte-packed hist
    __shared__ float s_rgrid[IPB][NN];             //  1,152 B
    __shared__ u32   s_wsel[IPB];                  //     32 B

    const int tid = threadIdx.x;
    const int bid = blockIdx.x;

    const int il    = tid & (IPB - 1);
    const int slice = tid >> 3;                    // 0..63
    const int i     = bid * IPB + il;

    const float2 pi = ((const float2*)obs2_g)[i];
    const float  xi4 = pi.x - 4.0f;
    const float  yi4 = pi.y - 4.0f;

    // self-pair bin via IDENTICAL arithmetic (handles fl(xi - fl(xi-4)) != 4)
    if (tid < IPB) {
        float dx = pi.x - xi4;
        float dy = pi.y - yi4;
        u32 u1 = (u32)((int)dx) - 1u;
        u32 u2 = (u32)((int)dy) - 1u;
        bool ok = (u1 < 6u) & (u2 < 6u);           // false iff NaN/inf row
        s_wsel[il] = ok ? (u1 * 6u + u2) : 255u;
    }

    // ---- Phase 1: pairwise histogram, all in registers (zero DS in loop)
    u64 R1=0, R2=0, R4=0, R8=0, R16=0, R32=0, R64=0;

    #define GRP8(r0, r1, r2, r3)                                             \
        add8(onehot_asm(r0.x, r0.y, xi4, yi4), onehot_asm(r0.z, r0.w, xi4, yi4), \
             onehot_asm(r1.x, r1.y, xi4, yi4), onehot_asm(r1.z, r1.w, xi4, yi4), \
             onehot_asm(r2.x, r2.y, xi4, yi4), onehot_asm(r2.z, r2.w, xi4, yi4), \
             onehot_asm(r3.x, r3.y, xi4, yi4), onehot_asm(r3.z, r3.w, xi4, yi4), \
             R1, R2, R4, R8, R16, R32, R64)

    {
        const float4* jp = (const float4*)obs2_g + slice * (JS / 2);  // 64 f4
        float4 a0 = jp[0], a1 = jp[1], a2 = jp[2], a3 = jp[3];
        float4 b0 = jp[4], b1 = jp[5], b2 = jp[6], b3 = jp[7];
        jp += 8;
        #pragma unroll 1
        for (int it = 0; it < 7; ++it) {          // 7 x 16 + 16 = 128 pairs
            GRP8(a0, a1, a2, a3);
            a0 = jp[0]; a1 = jp[1]; a2 = jp[2]; a3 = jp[3];
            GRP8(b0, b1, b2, b3);
            b0 = jp[4]; b1 = jp[5]; b2 = jp[6]; b3 = jp[7];
            jp += 8;
        }
        GRP8(a0, a1, a2, a3);
        GRP8(b0, b1, b2, b3);
    }
    #undef GRP8

    // ---- Flush: planes -> byte-packed counts, written (not added) to LDS.
    // nibble n -> 4 bytes via (n*0x00204081)&0x01010101 (carry-free), <<L.
    {
        const u32 lo[7] = { (u32)R1,  (u32)R2,  (u32)R4,  (u32)R8,
                            (u32)R16, (u32)R32, (u32)R64 };
        const u32 hi[7] = { (u32)(R1>>32),  (u32)(R2>>32),  (u32)(R4>>32),
                            (u32)(R8>>32),  (u32)(R16>>32), (u32)(R32>>32),
                            (u32)(R64>>32) };
        #pragma unroll
        for (int w = 0; w < 9; ++w) {
            u32 acc = 0;
            #pragma unroll
            for (int L = 0; L < 7; ++L) {
                u32 nib = (w < 8) ? ((lo[L] >> (4 * w)) & 0xFu)
                                  : (hi[L] & 0xFu);
                acc += ((nib * 0x00204081u) & 0x01010101u) << L;
            }
            s_h[w * BLOCK + tid] = acc;            // bank = tid%32, no conflict
        }
    }
    __syncthreads();

    // ---- Phase 2: byte-wise reduce over 64 slices (72 tasks)
    if (tid < IPB * 9) {                           // 72
        const int ril = tid & (IPB - 1);
        const int w   = tid >> 3;                  // 0..8
        u32 lo = 0u, hi = 0u;                      // 2x u16 lanes each
        #pragma unroll 8
        for (int sl = 0; sl < SLICES; ++sl) {
            u32 a = s_h[(w << 9) + sl * IPB + ril];
            lo += a & 0x00FF00FFu;
            hi += (a >> 8) & 0x00FF00FFu;
        }
        u32 s0 = lo & 0xFFFFu;
        u32 s1 = hi & 0xFFFFu;
        u32 s2 = lo >> 16;
        u32 s3 = hi >> 16;
        const u32 sel  = s_wsel[ril];
        const u32 base = (u32)(w * 4);
        s0 -= (sel == base + 0u);
        s1 -= (sel == base + 1u);
        s2 -= (sel == base + 2u);
        s3 -= (sel == base + 3u);
        s_rgrid[ril][base + 0] = (float)s0;
        s_rgrid[ril][base + 1] = (float)s1;
        s_rgrid[ril][base + 2] = (float)s2;
        s_rgrid[ril][base + 3] = (float)s3;
    }
    __syncthreads();

    // ---- Phase 3: fused GEMM  out[i][h] = sum_k grid[i][k]*W[h][k] + b[h]
    const int h  = tid & (HID - 1);                // 0..127
    const int r0 = tid >> 7;                       // 0..3 (wave-pair uniform)
    const float4* W4 = (const float4*)Wg;          // [128][9] float4

    const float bh = bias[h];
    float acc0 = bh, acc1 = bh;

    #pragma unroll
    for (int k4 = 0; k4 < 9; ++k4) {
        float4 w4 = W4[h * 9 + k4];
        float4 g0 = *(const float4*)&s_rgrid[r0    ][k4 * 4];
        float4 g1 = *(const float4*)&s_rgrid[r0 + 4][k4 * 4];
        acc0 += g0.x * w4.x + g0.y * w4.y + g0.z * w4.z + g0.w * w4.w;
        acc1 += g1.x * w4.x + g1.y * w4.y + g1.z * w4.z + g1.w * w4.w;
    }

    const int obase = bid * IPB;
    out[(obase + r0    ) * HID + h] = acc0;
    out[(obase + r0 + 4) * HID + h] = acc1;
}

extern "C" void kernel_launch(void* const* d_in, const int* in_sizes, int n_in,
                              void* d_out, int out_size, void* d_ws, size_t ws_size,
                              hipStream_t stream) {
    // inputs: 0=hidden_state (unused), 1=obs1 (unused), 2=obs2, 3=W, 4=b
    const float* obs2 = (const float*)d_in[2];
    const float* W    = (const float*)d_in[3];
    const float* b    = (const float*)d_in[4];
    float* out        = (float*)d_out;
    (void)in_sizes; (void)n_in; (void)out_size; (void)d_ws; (void)ws_size;

    hipLaunchKernelGGL(pool_kernel, dim3(NB), dim3(BLOCK), 0, stream,
                       obs2, W, b, out);
}